// Round 8
// baseline (2213.791 us; speedup 1.0000x reference)
//
#include <hip/hip_runtime.h>

typedef unsigned short u16;
typedef unsigned int   u32;
typedef _Float16 f16;
typedef f16  v8h __attribute__((ext_vector_type(8)));
typedef f16  v4h __attribute__((ext_vector_type(4)));
typedef short v8s __attribute__((ext_vector_type(8)));
typedef float v4f __attribute__((ext_vector_type(4)));
typedef u16   v4u __attribute__((ext_vector_type(4)));

__device__ __forceinline__ float bf2f(u16 u) {
    union { float f; u32 i; } c; c.i = ((u32)u) << 16; return c.f;
}
__device__ __forceinline__ u16 f2bf(float f) {
    union { float f; u32 i; } c; c.f = f;
    u32 x = c.i;
    return (u16)((x + 0x7fffu + ((x >> 16) & 1u)) >> 16);
}
__device__ __forceinline__ float ldw(const void* p, long i, int flag) {
    return flag ? bf2f(((const u16*)p)[i]) : ((const float*)p)[i];
}

// ---------------------------------------------------------------------------
// dtype detector + split-K counter zeroing (counters in meta[64..127]).
// Runs once per kernel_launch, so workspace re-poisoning can't corrupt the
// semaphore counters.
// ---------------------------------------------------------------------------
__global__ void detect_k(const u32* __restrict__ w, u32* __restrict__ meta) {
    __shared__ int cnt;
    if (threadIdx.x < 64) meta[64 + threadIdx.x] = 0u;   // zero tile counters
    if (threadIdx.x == 0) cnt = 0;
    __syncthreads();
    u32 v = w[(size_t)threadIdx.x * 4099];
    u32 f = (v >> 7) & 0xFFu;
    if (f >= 0x60u && f < 0x7Fu) atomicAdd(&cnt, 1);
    __syncthreads();
    if (threadIdx.x == 0) meta[0] = (cnt >= 192) ? 1u : 0u;
}

// Convert input (bf16 or fp32 per flag) -> fp16, 4 elems/thread.
__global__ void cvt_half(const void* __restrict__ in, f16* __restrict__ out,
                         const u32* __restrict__ meta, int n) {
    const int flag = meta[0];
    const int n4 = n >> 2;
    const int stride = gridDim.x * blockDim.x;
    for (int i = blockIdx.x * blockDim.x + threadIdx.x; i < n4; i += stride) {
        v4h o;
        if (flag) {
            v4u h = *(const v4u*)((const u16*)in + (size_t)i * 4);
            #pragma unroll
            for (int r = 0; r < 4; ++r) o[r] = (f16)bf2f(h[r]);
        } else {
            v4f v = *(const v4f*)((const float*)in + (size_t)i * 4);
            #pragma unroll
            for (int r = 0; r < 4; ++r) o[r] = (f16)v[r];
        }
        *(v4h*)(out + (size_t)i * 4) = o;
    }
}

// One-time W2 transpose: W2[f*25+kc][fo] -> W2t16[fo][kc*32+f] (fp16)
__global__ void w2t_k(const void* __restrict__ W2, const u32* __restrict__ meta,
                      f16* __restrict__ W2t16) {
    const int flag = meta[0];
    const int i = blockIdx.x * 256 + threadIdx.x;
    if (i >= 51200) return;
    const int k = i >> 6, fo = i & 63;
    const float w = ldw(W2, (size_t)k * 64 + fo, flag);
    const int f = k / 25, kc = k % 25;
    W2t16[(size_t)fo * 800 + kc * 32 + f] = (f16)w;
}

// ---------------------------------------------------------------------------
// Tiled Cheb GEMM (fp16 single-product): C = alpha*L@B - A
// Block: 64x64 tile, 256 thr = 4 waves (2x2), wave 32x32 via 2x2 MFMA
// 16x16x32 f16. Double-buffered LDS (36 KB; 2 blocks/CU), one barrier per
// K-stage, software pipeline depth 2 (P,Q register sets). [R7 validated]
// Round-8 change (FUSED=0 only): split-K combine FUSED via last-block
// semaphore — each z-block writes fp32 partials, release-fence, atomicAdd
// on per-m-tile counter; 8th arrival acquire-fences and does the combine +
// recurrence epilogue (identical arithmetic/order to the old cheb_comb ->
// bit-identical output). Eliminates 24 comb dispatches per run.
// FUSED=1: recurrence epilogue + Xt write (layer 2) — unchanged from R7.
// ---------------------------------------------------------------------------
template<int FUSED>
__global__ __launch_bounds__(256) void cheb_tile(
    const f16* __restrict__ L, const f16* __restrict__ B, const f16* __restrict__ A,
    f16* __restrict__ C, float* __restrict__ Cpart, f16* __restrict__ Xt,
    int M, int V, int NC, int kc, float alpha, int useA, u32* __restrict__ cnt)
{
    __shared__ f16 smem[2 * 2 * 64 * 72];        // dbuf x (A|B) x [64][72] = 36 KB
    const int tid  = threadIdx.x;
    const int wave = tid >> 6;
    const int lane = tid & 63;
    const int r16  = lane & 15;
    const int quad = lane >> 4;
    const int wm = wave & 1, wn = wave >> 1;

    const int m0 = blockIdx.x * 64;
    const int n0 = blockIdx.y * 64;
    const int k0 = blockIdx.z * kc;

    const int sr = lane >> 3;                    // 0..7
    const int sc = lane & 7;                     // 0..7
    const int rloc = wave * 16 + sr;             // row, j=0 (+8 rows for j=1)
    const int lw  = rloc * 72 + sc * 8;

    v4f acc[2][2];
    #pragma unroll
    for (int i = 0; i < 2; ++i)
        #pragma unroll
        for (int j = 0; j < 2; ++j) acc[i][j] = (v4f){0.f, 0.f, 0.f, 0.f};

    const int arow0 = (wm * 32 + r16) * 72;      // offsets within one 9216-elem buf
    const int arow1 = arow0 + 16 * 72;
    const int brow0 = 4608 + (wn * 32 + r16) * 72;
    const int brow1 = brow0 + 16 * 72;

    const int stages = kc >> 6;                  // 8 (layer 1) or 16 (layer 2); even
    const size_t j8  = (size_t)8 * V;
    const size_t gAr = (size_t)(m0 + rloc) * V + sc * 8;
    const size_t gBr = (size_t)(n0 + rloc) * V + sc * 8;

#define LOADG(KK, T0, T1, T2, T3) {                                   \
    const size_t gA = gAr + (size_t)(KK);                             \
    const size_t gB = gBr + (size_t)(KK);                             \
    T0 = *(const v8h*)(L + gA); T1 = *(const v8h*)(L + gA + j8);      \
    T2 = *(const v8h*)(B + gB); T3 = *(const v8h*)(B + gB + j8); }

#define WRITELDS(BUF, T0, T1, T2, T3) {                               \
    f16* sn = smem + (BUF) * 9216;                                    \
    *(v8h*)(sn +        lw)       = T0;                               \
    *(v8h*)(sn +        lw + 576) = T1;                               \
    *(v8h*)(sn + 4608 + lw)       = T2;                               \
    *(v8h*)(sn + 4608 + lw + 576) = T3; }

#define COMPUTE(BUF) {                                                \
    const f16* scur = smem + (BUF) * 9216;                            \
    _Pragma("unroll")                                                 \
    for (int s = 0; s < 2; ++s) {                                     \
        const int qo = (s * 4 + quad) * 8;                            \
        v8h a0 = *(const v8h*)(scur + arow0 + qo);                    \
        v8h a1 = *(const v8h*)(scur + arow1 + qo);                    \
        v8h b0 = *(const v8h*)(scur + brow0 + qo);                    \
        v8h b1 = *(const v8h*)(scur + brow1 + qo);                    \
        acc[0][0] = __builtin_amdgcn_mfma_f32_16x16x32_f16(a0, b0, acc[0][0], 0, 0, 0); \
        acc[0][1] = __builtin_amdgcn_mfma_f32_16x16x32_f16(a0, b1, acc[0][1], 0, 0, 0); \
        acc[1][0] = __builtin_amdgcn_mfma_f32_16x16x32_f16(a1, b0, acc[1][0], 0, 0, 0); \
        acc[1][1] = __builtin_amdgcn_mfma_f32_16x16x32_f16(a1, b1, acc[1][1], 0, 0, 0); } }

    // prologue: stage 0 -> LDS buf 0; prefetch stages 1 (P) and 2 (Q)
    {
        v8h t0, t1, t2, t3;
        LOADG(k0, t0, t1, t2, t3);
        WRITELDS(0, t0, t1, t2, t3);
    }
    v8h p0, p1, p2, p3, q0, q1, q2, q3;
    if (1 < stages) LOADG(k0 + 64,  p0, p1, p2, p3);
    if (2 < stages) LOADG(k0 + 128, q0, q1, q2, q3);
    __syncthreads();

    for (int st = 0; st < stages; st += 2) {
        // ---- stage st (even): compute buf 0 ----
        COMPUTE(0);
        if (st + 1 < stages) {
            WRITELDS(1, p0, p1, p2, p3);          // waits only P's loads
            if (st + 3 < stages) LOADG(k0 + (st + 3) * 64, p0, p1, p2, p3);
            __syncthreads();
            // ---- stage st+1 (odd): compute buf 1 ----
            COMPUTE(1);
            if (st + 2 < stages) {
                WRITELDS(0, q0, q1, q2, q3);
                if (st + 4 < stages) LOADG(k0 + (st + 4) * 64, q0, q1, q2, q3);
                __syncthreads();
            }
        }
    }

#undef LOADG
#undef WRITELDS
#undef COMPUTE

    if (FUSED) {
        #pragma unroll
        for (int j = 0; j < 2; ++j) {
            const int n = n0 + wn * 32 + j * 16 + r16;
            #pragma unroll
            for (int i = 0; i < 2; ++i) {
                const int mrow = m0 + wm * 32 + i * 16 + quad * 4;
                const size_t obase = (size_t)n * M + mrow;
                float vals[4];
                if (useA) {
                    v4h a4 = *(const v4h*)(A + obase);
                    #pragma unroll
                    for (int r = 0; r < 4; ++r)
                        vals[r] = alpha * acc[i][j][r] - (float)a4[r];
                } else {
                    #pragma unroll
                    for (int r = 0; r < 4; ++r) vals[r] = alpha * acc[i][j][r];
                }
                v4h co;
                #pragma unroll
                for (int r = 0; r < 4; ++r) co[r] = (f16)vals[r];
                *(v4h*)(C + obase) = co;
                // transposed copy for lin2 MFMA: Xt[(nb*1024 + u)*32 + f]
                const int nb = n >> 5, f = n & 31;
                f16* xt = Xt + ((size_t)(nb * 1024) + mrow) * 32 + f;
                #pragma unroll
                for (int r = 0; r < 4; ++r) xt[r * 32] = co[r];
            }
        }
    } else {
        // ---- write fp32 partials (layout unchanged from R7) ----
        #pragma unroll
        for (int j = 0; j < 2; ++j) {
            const int n = n0 + wn * 32 + j * 16 + r16;
            #pragma unroll
            for (int i = 0; i < 2; ++i) {
                const int mrow = m0 + wm * 32 + i * 16 + quad * 4;
                float* cp = Cpart + ((size_t)(blockIdx.z * NC + n)) * M + mrow;
                *(v4f*)cp = acc[i][j];
            }
        }
        // ---- fused split-K combine: last-arriving z-block reduces ----
        __threadfence();                          // release partials (device)
        __syncthreads();
        __shared__ int lastArr;
        if (tid == 0) {
            u32 old = atomicAdd(&cnt[blockIdx.x], 1u);
            lastArr = ((old & 7u) == 7u) ? 1 : 0;   // gridDim.z == 8
        }
        __syncthreads();
        if (lastArr) {
            __threadfence();                      // acquire: see siblings' partials
            // combine m-tile [m0,m0+64): 64 n x 16 m-quads = 1024 v4 units
            for (int u = tid; u < 1024; u += 256) {
                const int n  = u >> 4;
                const int mq = m0 + ((u & 15) << 2);
                float s0 = 0.f, s1 = 0.f, s2 = 0.f, s3 = 0.f;
                #pragma unroll
                for (int c = 0; c < 8; ++c) {
                    v4f p = *(const v4f*)(Cpart + ((size_t)(c * 64 + n)) * M + mq);
                    s0 += p[0]; s1 += p[1]; s2 += p[2]; s3 += p[3];
                }
                const size_t bidx = (size_t)n * M + mq;
                v4h o;
                if (useA) {
                    v4h a4 = *(const v4h*)(A + bidx);
                    o[0] = (f16)(alpha * s0 - (float)a4[0]);
                    o[1] = (f16)(alpha * s1 - (float)a4[1]);
                    o[2] = (f16)(alpha * s2 - (float)a4[2]);
                    o[3] = (f16)(alpha * s3 - (float)a4[3]);
                } else {
                    o[0] = (f16)(alpha * s0);
                    o[1] = (f16)(alpha * s1);
                    o[2] = (f16)(alpha * s2);
                    o[3] = (f16)(alpha * s3);
                }
                *(v4h*)(C + bidx) = o;
            }
        }
    }
}

// ---------------------------------------------------------------------------
// Linear1 (25->32) + bias + relu + maxpool4 -> layer-2 slice0 (fp16) + Xt0.
// Each thread: 8 input m (16-B loads) -> 2 pooled outputs.
// ---------------------------------------------------------------------------
__global__ __launch_bounds__(256) void lin1_pool(
    const f16* __restrict__ S, const void* __restrict__ W1, const void* __restrict__ b1,
    const u32* __restrict__ meta, f16* __restrict__ O, f16* __restrict__ Xt0)
{
    const int flag = meta[0];
    const int g  = blockIdx.x * 64 + threadIdx.x;   // 0..511
    const int f  = blockIdx.y * 4 + threadIdx.y;    // 0..31
    const int n  = blockIdx.z;                      // 0..63
    float a[8];
    #pragma unroll
    for (int r = 0; r < 8; ++r) a[r] = 0.f;
    const size_t base = (size_t)n * 4096 + (size_t)g * 8;
    #pragma unroll
    for (int k = 0; k < 25; ++k) {
        v8h x8 = *(const v8h*)(S + (size_t)k * 262144 + base);
        float w = ldw(W1, k * 32 + f, flag);
        #pragma unroll
        for (int r = 0; r < 8; ++r) a[r] += (float)x8[r] * w;
    }
    const float b = ldw(b1, f, flag);
    float v0 = fmaxf(fmaxf(fmaxf(a[0], a[1]), fmaxf(a[2], a[3])) + b, 0.f);
    float v1 = fmaxf(fmaxf(fmaxf(a[4], a[5]), fmaxf(a[6], a[7])) + b, 0.f);
    const int m1 = g * 2;
    const size_t oi = ((size_t)n * 32 + f) * 1024 + m1;
    O[oi]     = (f16)v0;
    O[oi + 1] = (f16)v1;
    f16* xt = Xt0 + ((size_t)n * 1024 + m1) * 32 + f;
    xt[0]  = (f16)v0;
    xt[32] = (f16)v1;
}

// ---------------------------------------------------------------------------
// MFMA linear-2 accumulation over a group of up to 5 slices (fp16 single).
// Xt ring has 5 slots; slice k lives in slot k%5 (k0 is a multiple of 5).
// [ring-of-5 validated rounds 1-7]
// ---------------------------------------------------------------------------
__global__ __launch_bounds__(256) void lin2_mfma(
    const f16* __restrict__ XtBase, const f16* __restrict__ W2t16,
    float* __restrict__ acc, int k0, int cnt, int zi)
{
    const int tid  = threadIdx.x;
    const int wave = tid >> 6;
    const int lane = tid & 63;
    const int r16  = lane & 15;
    const int quad = lane >> 4;
    const int n  = blockIdx.y;
    const int u0 = blockIdx.x * 128 + wave * 32;

    v4f a[2][4];
    #pragma unroll
    for (int i = 0; i < 2; ++i)
        #pragma unroll
        for (int j = 0; j < 4; ++j) a[i][j] = (v4f){0.f, 0.f, 0.f, 0.f};

    for (int c = 0; c < cnt; ++c) {
        const f16* X = XtBase + (size_t)((k0 + c) % 5) * 2097152;
        v8h a0 = *(const v8h*)(X + ((size_t)n * 1024 + u0 + r16) * 32 + quad * 8);
        v8h a1 = *(const v8h*)(X + ((size_t)n * 1024 + u0 + 16 + r16) * 32 + quad * 8);
        const int kb = (k0 + c) * 32 + quad * 8;
        #pragma unroll
        for (int j = 0; j < 4; ++j) {
            v8h bh = *(const v8h*)(W2t16 + (size_t)(j * 16 + r16) * 800 + kb);
            a[0][j] = __builtin_amdgcn_mfma_f32_16x16x32_f16(a0, bh, a[0][j], 0, 0, 0);
            a[1][j] = __builtin_amdgcn_mfma_f32_16x16x32_f16(a1, bh, a[1][j], 0, 0, 0);
        }
    }

    #pragma unroll
    for (int i = 0; i < 2; ++i) {
        const int u = u0 + i * 16 + quad * 4;
        #pragma unroll
        for (int j = 0; j < 4; ++j) {
            const int fo = j * 16 + r16;
            float* p = acc + ((size_t)n * 1024 + u) * 64 + fo;
            if (zi) {
                #pragma unroll
                for (int r = 0; r < 4; ++r) p[r * 64] = a[i][j][r];
            } else {
                #pragma unroll
                for (int r = 0; r < 4; ++r) p[r * 64] += a[i][j][r];
            }
        }
    }
}

// Finish linear-2: bias + relu + maxpool4 -> hb16 bf16 hi/lo pair [n][16384]
__global__ __launch_bounds__(256) void lin2fin(
    const float* __restrict__ acc, const void* __restrict__ b2, const u32* __restrict__ meta,
    u16* __restrict__ hb16h, u16* __restrict__ hb16l)
{
    const int flag = meta[0];
    const int fo = threadIdx.x;
    const int m2 = blockIdx.x * 4 + threadIdx.y;
    const int n  = blockIdx.y;
    const size_t b = ((size_t)n * 1024 + (size_t)m2 * 4) * 64 + fo;
    float v = fmaxf(fmaxf(acc[b], acc[b + 64]), fmaxf(acc[b + 128], acc[b + 192]));
    v = fmaxf(v + ldw(b2, fo, flag), 0.f);
    const size_t oi = (size_t)n * 16384 + (size_t)m2 * 64 + fo;
    const u16 h = f2bf(v);
    hb16h[oi] = h;
    hb16l[oi] = f2bf(v - bf2f(h));
}

// ---------------------------------------------------------------------------
// FC1 via MFMA: (64 x 16384) @ (16384 x 512), split-K x128, no atomics.
// Grid (32 nt, 32 kg), 4 waves; wave kc = kg*4+wave (K-chunk 128).
// ---------------------------------------------------------------------------
__global__ __launch_bounds__(256) void fc1_mfma(
    const u16* __restrict__ hb16h, const u16* __restrict__ hb16l,
    const void* __restrict__ Wh, const u32* __restrict__ meta,
    float* __restrict__ part128)
{
    const int flag = meta[0];
    const int tid  = threadIdx.x;
    const int wave = tid >> 6;
    const int lane = tid & 63;
    const int r16  = lane & 15;
    const int quad = lane >> 4;
    const int nt = blockIdx.x;                 // 0..31 -> h-tile of 16
    const int kc = blockIdx.y * 4 + wave;      // 0..127 -> K-chunk of 128

    v4f acc[4];
    #pragma unroll
    for (int mt = 0; mt < 4; ++mt) acc[mt] = (v4f){0.f, 0.f, 0.f, 0.f};

    const int h0 = nt * 16 + r16;
    for (int ks = 0; ks < 4; ++ks) {
        const int kb = kc * 128 + ks * 32 + quad * 8;
        v8s bh, bl;
        #pragma unroll
        for (int j = 0; j < 8; ++j) {
            const float w = ldw(Wh, (size_t)(kb + j) * 512 + h0, flag);
            const u16 h = f2bf(w);
            bh[j] = (short)h;
            bl[j] = (short)f2bf(w - bf2f(h));
        }
        #pragma unroll
        for (int mt = 0; mt < 4; ++mt) {
            const size_t arow = (size_t)(mt * 16 + r16) * 16384 + kb;
            v8s ah = *(const v8s*)(hb16h + arow);
            v8s al = *(const v8s*)(hb16l + arow);
            acc[mt] = __builtin_amdgcn_mfma_f32_16x16x32_bf16(ah, bh, acc[mt], 0, 0, 0);
            acc[mt] = __builtin_amdgcn_mfma_f32_16x16x32_bf16(ah, bl, acc[mt], 0, 0, 0);
            acc[mt] = __builtin_amdgcn_mfma_f32_16x16x32_bf16(al, bh, acc[mt], 0, 0, 0);
        }
    }

    #pragma unroll
    for (int mt = 0; mt < 4; ++mt) {
        const int m = mt * 16 + quad * 4;
        float* p = part128 + (size_t)kc * 32768 + (size_t)m * 512 + h0;
        #pragma unroll
        for (int r = 0; r < 4; ++r) p[r * 512] = acc[mt][r];
    }
}

// Combine fc1 split-K partials: partC[idx] = sum_c part128[c][idx]
__global__ __launch_bounds__(256) void fc1comb(
    const float* __restrict__ part128, float* __restrict__ partC)
{
    const int idx = blockIdx.x * 256 + threadIdx.x;   // 0..32767
    float s = 0.f;
    #pragma unroll 8
    for (int c = 0; c < 128; ++c) s += part128[(size_t)c * 32768 + idx];
    partC[idx] = s;
}

// FC1 bias + relu fused with FC2
__global__ void fc2_k(
    const float* __restrict__ partC, const void* __restrict__ bh,
    const void* __restrict__ Wo, const void* __restrict__ bo,
    const u32* __restrict__ meta, void* __restrict__ out)
{
    const int flag = meta[0];
    const int n = blockIdx.x;
    const int lane = threadIdx.x;   // 64 = 1 wave
    float p[10];
    #pragma unroll
    for (int o = 0; o < 10; ++o) p[o] = 0.f;
    for (int j = lane; j < 512; j += 64) {
        const float r = fmaxf(partC[(size_t)n * 512 + j] + ldw(bh, j, flag), 0.f);
        #pragma unroll
        for (int o = 0; o < 10; ++o) p[o] += r * ldw(Wo, j * 10 + o, flag);
    }
    #pragma unroll
    for (int o = 0; o < 10; ++o) {
        for (int off = 32; off > 0; off >>= 1) p[o] += __shfl_down(p[o], off);
    }
    if (lane == 0) {
        #pragma unroll
        for (int o = 0; o < 10; ++o) {
            float v = p[o] + ldw(bo, o, flag);
            if (flag) ((u16*)out)[n * 10 + o] = f2bf(v);
            else      ((float*)out)[n * 10 + o] = v;
        }
    }
}

extern "C" void kernel_launch(void* const* d_in, const int* in_sizes, int n_in,
                              void* d_out, int out_size, void* d_ws, size_t ws_size,
                              hipStream_t stream)
{
    const void* x  = d_in[0];
    const void* L0 = d_in[1];
    const void* L1 = d_in[2];
    const void* W1 = d_in[3];
    const void* b1 = d_in[4];
    const void* W2 = d_in[5];
    const void* b2 = d_in[6];
    const void* Wh = d_in[7];
    const void* bh = d_in[8];
    const void* Wo = d_in[9];
    const void* bo = d_in[10];

    // ---- workspace carve-up (~104 MB; meta extended 256 -> 512 B for
    //      split-K semaphore counters) ----
    char* base = (char*)d_ws;
    size_t off = 0;
    u32* meta  = (u32*)(base + off);     off += 512;
    f16* L016  = (f16*)(base + off);     off += (size_t)16777216 * 2;
    f16* L116  = (f16*)(base + off);     off += (size_t)1048576 * 2;
    f16* A116  = (f16*)(base + off);     off += (size_t)25 * 262144 * 2;
    f16* A216  = (f16*)(base + off);     off += (size_t)3 * 2097152 * 2;
    f16* Xt16  = (f16*)(base + off);     off += (size_t)5 * 2097152 * 2;  // ring of 5
    float* ACC2 = (float*)(base + off);  off += (size_t)16777216;
    u16* hb16h = (u16*)(base + off);     off += (size_t)2097152;
    u16* hb16l = (u16*)(base + off);     off += (size_t)2097152;
    float* partC = (float*)(base + off); off += (size_t)131072 * 4;
    f16* W2t16 = (f16*)(base + off);     off += (size_t)102400;
    // Overlays on ACC2 (16.78 MB), used in disjoint phases:
    //   cpart  (8.39 MB) — layer-1 split-K partials, dead before lin2_mfma zi=1
    //   part128 (16.78 MB) — fc1 partials, ACC2 dead after lin2fin
    float* cpart   = ACC2;
    float* part128 = ACC2;
    u32* tileCnt   = meta + 64;          // 64 per-m-tile semaphore counters

    // dtype detection (+ counter zeroing) + fp16 conversion + W2 transpose
    detect_k<<<1, 256, 0, stream>>>((const u32*)L0, meta);
    cvt_half<<<2048, 256, 0, stream>>>(L0, L016, meta, 16777216);
    cvt_half<<<256, 256, 0, stream>>>(L1, L116, meta, 1048576);
    cvt_half<<<64, 256, 0, stream>>>(x, A116, meta, 262144);   // slice 0
    w2t_k<<<200, 256, 0, stream>>>(W2, meta, W2t16);

    // ---- layer-1 Chebyshev recurrence: tiled split-K x8, combine fused via
    //      last-block semaphore (24 dispatches instead of 48) ----
    for (int k = 1; k < 25; ++k) {
        const f16* pA = (k >= 2) ? A116 + (size_t)(k - 2) * 262144 : A116;
        cheb_tile<0><<<dim3(64, 1, 8), 256, 0, stream>>>(
            L016, A116 + (size_t)(k - 1) * 262144, pA,
            A116 + (size_t)k * 262144, cpart, (f16*)0,
            4096, 4096, 64, 512, (k == 1) ? 1.f : 2.f, (k >= 2) ? 1 : 0,
            tileCnt);
    }

    // linear1 + relu + pool4 -> layer-2 slice 0 (fp16) + transposed Xt slot 0
    lin1_pool<<<dim3(8, 8, 64), dim3(64, 4), 0, stream>>>(
        A116, W1, b1, meta, A216, Xt16);

    // ---- layer-2 recurrence (tiled, fused epilogue + Xt) + grouped MFMA lin2
    for (int k = 1; k < 25; ++k) {
        const f16* pB = A216 + (size_t)((k - 1) % 3) * 2097152;
        const f16* pA = A216 + (size_t)(((k >= 2) ? (k - 2) : 0) % 3) * 2097152;
        f16* pC = A216 + (size_t)(k % 3) * 2097152;
        cheb_tile<1><<<dim3(16, 32, 1), 256, 0, stream>>>(
            L116, pB, pA, pC, (float*)0, Xt16 + (size_t)(k % 5) * 2097152,
            1024, 1024, 2048, 1024, (k == 1) ? 1.f : 2.f, (k >= 2) ? 1 : 0,
            (u32*)0);
        if ((k + 1) % 5 == 0) {
            // slices k-4..k occupy Xt slots 0..4 (k-4 is a multiple of 5)
            lin2_mfma<<<dim3(8, 64), 256, 0, stream>>>(
                Xt16, W2t16, ACC2, k - 4, 5, (k == 4) ? 1 : 0);
        }
    }

    // finish linear2: bias + relu + pool4 -> hb16 bf16 pair (ACC2 dead after)
    lin2fin<<<dim3(64, 64), dim3(64, 4), 0, stream>>>(ACC2, b2, meta, hb16h, hb16l);

    // FC head: MFMA fc1 (split-K x128, no atomics) + combine + fc2
    fc1_mfma<<<dim3(32, 32), 256, 0, stream>>>(hb16h, hb16l, Wh, meta, part128);
    fc1comb<<<128, 256, 0, stream>>>(part128, partC);
    fc2_k<<<64, 64, 0, stream>>>(partC, bh, Wo, bo, meta, d_out);
}

// Round 9
// 873.313 us; speedup vs baseline: 2.5349x; 2.5349x over previous
//
#include <hip/hip_runtime.h>

typedef unsigned short u16;
typedef unsigned int   u32;
typedef _Float16 f16;
typedef f16  v8h __attribute__((ext_vector_type(8)));
typedef f16  v4h __attribute__((ext_vector_type(4)));
typedef short v8s __attribute__((ext_vector_type(8)));
typedef float v4f __attribute__((ext_vector_type(4)));
typedef u16   v4u __attribute__((ext_vector_type(4)));

__device__ __forceinline__ float bf2f(u16 u) {
    union { float f; u32 i; } c; c.i = ((u32)u) << 16; return c.f;
}
__device__ __forceinline__ u16 f2bf(float f) {
    union { float f; u32 i; } c; c.f = f;
    u32 x = c.i;
    return (u16)((x + 0x7fffu + ((x >> 16) & 1u)) >> 16);
}
__device__ __forceinline__ float ldw(const void* p, long i, int flag) {
    return flag ? bf2f(((const u16*)p)[i]) : ((const float*)p)[i];
}

// ---------------------------------------------------------------------------
// dtype detector (round-3 validated: flag=0 on this harness -> fp32 inputs)
// ---------------------------------------------------------------------------
__global__ void detect_k(const u32* __restrict__ w, u32* __restrict__ meta) {
    __shared__ int cnt;
    if (threadIdx.x == 0) cnt = 0;
    __syncthreads();
    u32 v = w[(size_t)threadIdx.x * 4099];
    u32 f = (v >> 7) & 0xFFu;
    if (f >= 0x60u && f < 0x7Fu) atomicAdd(&cnt, 1);
    __syncthreads();
    if (threadIdx.x == 0) meta[0] = (cnt >= 192) ? 1u : 0u;
}

// Convert input (bf16 or fp32 per flag) -> fp16, 4 elems/thread.
__global__ void cvt_half(const void* __restrict__ in, f16* __restrict__ out,
                         const u32* __restrict__ meta, int n) {
    const int flag = meta[0];
    const int n4 = n >> 2;
    const int stride = gridDim.x * blockDim.x;
    for (int i = blockIdx.x * blockDim.x + threadIdx.x; i < n4; i += stride) {
        v4h o;
        if (flag) {
            v4u h = *(const v4u*)((const u16*)in + (size_t)i * 4);
            #pragma unroll
            for (int r = 0; r < 4; ++r) o[r] = (f16)bf2f(h[r]);
        } else {
            v4f v = *(const v4f*)((const float*)in + (size_t)i * 4);
            #pragma unroll
            for (int r = 0; r < 4; ++r) o[r] = (f16)v[r];
        }
        *(v4h*)(out + (size_t)i * 4) = o;
    }
}

// One-time W2 transpose: W2[f*25+kc][fo] -> W2t16[fo][kc*32+f] (fp16)
__global__ void w2t_k(const void* __restrict__ W2, const u32* __restrict__ meta,
                      f16* __restrict__ W2t16) {
    const int flag = meta[0];
    const int i = blockIdx.x * 256 + threadIdx.x;
    if (i >= 51200) return;
    const int k = i >> 6, fo = i & 63;
    const float w = ldw(W2, (size_t)k * 64 + fo, flag);
    const int f = k / 25, kc = k % 25;
    W2t16[(size_t)fo * 800 + kc * 32 + f] = (f16)w;
}

// ---------------------------------------------------------------------------
// Tiled Cheb GEMM (fp16 single-product): C = alpha*L@B - A
// Block: 64x64 tile, 256 thr = 4 waves (2x2), wave 32x32 via 2x2 MFMA
// 16x16x32 f16. Double-buffered LDS (36 KB; 2 blocks/CU), one barrier per
// K-stage, software pipeline depth 2 (P,Q register sets). [R7 champion,
// restored verbatim. R8's fence-based combine fusion REVERTED: device-scope
// __threadfence per block forces L2 writeback on gfx950 (non-coherent
// per-XCD L2) — measured 9 -> 72 us/dispatch.]
// FUSED=1: recurrence epilogue + Xt write (layer 2). FUSED=0: fp32 split-K
// partials (layer 1).
// ---------------------------------------------------------------------------
template<int FUSED>
__global__ __launch_bounds__(256) void cheb_tile(
    const f16* __restrict__ L, const f16* __restrict__ B, const f16* __restrict__ A,
    f16* __restrict__ C, float* __restrict__ Cpart, f16* __restrict__ Xt,
    int M, int V, int NC, int kc, float alpha, int useA)
{
    __shared__ f16 smem[2 * 2 * 64 * 72];        // dbuf x (A|B) x [64][72] = 36 KB
    const int tid  = threadIdx.x;
    const int wave = tid >> 6;
    const int lane = tid & 63;
    const int r16  = lane & 15;
    const int quad = lane >> 4;
    const int wm = wave & 1, wn = wave >> 1;

    const int m0 = blockIdx.x * 64;
    const int n0 = blockIdx.y * 64;
    const int k0 = blockIdx.z * kc;

    const int sr = lane >> 3;                    // 0..7
    const int sc = lane & 7;                     // 0..7
    const int rloc = wave * 16 + sr;             // row, j=0 (+8 rows for j=1)
    const int lw  = rloc * 72 + sc * 8;

    v4f acc[2][2];
    #pragma unroll
    for (int i = 0; i < 2; ++i)
        #pragma unroll
        for (int j = 0; j < 2; ++j) acc[i][j] = (v4f){0.f, 0.f, 0.f, 0.f};

    const int arow0 = (wm * 32 + r16) * 72;      // offsets within one 9216-elem buf
    const int arow1 = arow0 + 16 * 72;
    const int brow0 = 4608 + (wn * 32 + r16) * 72;
    const int brow1 = brow0 + 16 * 72;

    const int stages = kc >> 6;                  // 8 (layer 1) or 16 (layer 2); even
    const size_t j8  = (size_t)8 * V;
    const size_t gAr = (size_t)(m0 + rloc) * V + sc * 8;
    const size_t gBr = (size_t)(n0 + rloc) * V + sc * 8;

#define LOADG(KK, T0, T1, T2, T3) {                                   \
    const size_t gA = gAr + (size_t)(KK);                             \
    const size_t gB = gBr + (size_t)(KK);                             \
    T0 = *(const v8h*)(L + gA); T1 = *(const v8h*)(L + gA + j8);      \
    T2 = *(const v8h*)(B + gB); T3 = *(const v8h*)(B + gB + j8); }

#define WRITELDS(BUF, T0, T1, T2, T3) {                               \
    f16* sn = smem + (BUF) * 9216;                                    \
    *(v8h*)(sn +        lw)       = T0;                               \
    *(v8h*)(sn +        lw + 576) = T1;                               \
    *(v8h*)(sn + 4608 + lw)       = T2;                               \
    *(v8h*)(sn + 4608 + lw + 576) = T3; }

#define COMPUTE(BUF) {                                                \
    const f16* scur = smem + (BUF) * 9216;                            \
    _Pragma("unroll")                                                 \
    for (int s = 0; s < 2; ++s) {                                     \
        const int qo = (s * 4 + quad) * 8;                            \
        v8h a0 = *(const v8h*)(scur + arow0 + qo);                    \
        v8h a1 = *(const v8h*)(scur + arow1 + qo);                    \
        v8h b0 = *(const v8h*)(scur + brow0 + qo);                    \
        v8h b1 = *(const v8h*)(scur + brow1 + qo);                    \
        acc[0][0] = __builtin_amdgcn_mfma_f32_16x16x32_f16(a0, b0, acc[0][0], 0, 0, 0); \
        acc[0][1] = __builtin_amdgcn_mfma_f32_16x16x32_f16(a0, b1, acc[0][1], 0, 0, 0); \
        acc[1][0] = __builtin_amdgcn_mfma_f32_16x16x32_f16(a1, b0, acc[1][0], 0, 0, 0); \
        acc[1][1] = __builtin_amdgcn_mfma_f32_16x16x32_f16(a1, b1, acc[1][1], 0, 0, 0); } }

    // prologue: stage 0 -> LDS buf 0; prefetch stages 1 (P) and 2 (Q)
    {
        v8h t0, t1, t2, t3;
        LOADG(k0, t0, t1, t2, t3);
        WRITELDS(0, t0, t1, t2, t3);
    }
    v8h p0, p1, p2, p3, q0, q1, q2, q3;
    if (1 < stages) LOADG(k0 + 64,  p0, p1, p2, p3);
    if (2 < stages) LOADG(k0 + 128, q0, q1, q2, q3);
    __syncthreads();

    for (int st = 0; st < stages; st += 2) {
        // ---- stage st (even): compute buf 0 ----
        COMPUTE(0);
        if (st + 1 < stages) {
            WRITELDS(1, p0, p1, p2, p3);          // waits only P's loads
            if (st + 3 < stages) LOADG(k0 + (st + 3) * 64, p0, p1, p2, p3);
            __syncthreads();
            // ---- stage st+1 (odd): compute buf 1 ----
            COMPUTE(1);
            if (st + 2 < stages) {
                WRITELDS(0, q0, q1, q2, q3);
                if (st + 4 < stages) LOADG(k0 + (st + 4) * 64, q0, q1, q2, q3);
                __syncthreads();
            }
        }
    }

#undef LOADG
#undef WRITELDS
#undef COMPUTE

    #pragma unroll
    for (int j = 0; j < 2; ++j) {
        const int n = n0 + wn * 32 + j * 16 + r16;
        #pragma unroll
        for (int i = 0; i < 2; ++i) {
            const int mrow = m0 + wm * 32 + i * 16 + quad * 4;
            if (FUSED) {
                const size_t obase = (size_t)n * M + mrow;
                float vals[4];
                if (useA) {
                    v4h a4 = *(const v4h*)(A + obase);
                    #pragma unroll
                    for (int r = 0; r < 4; ++r)
                        vals[r] = alpha * acc[i][j][r] - (float)a4[r];
                } else {
                    #pragma unroll
                    for (int r = 0; r < 4; ++r) vals[r] = alpha * acc[i][j][r];
                }
                v4h co;
                #pragma unroll
                for (int r = 0; r < 4; ++r) co[r] = (f16)vals[r];
                *(v4h*)(C + obase) = co;
                // transposed copy for lin2 MFMA: Xt[(nb*1024 + u)*32 + f]
                const int nb = n >> 5, f = n & 31;
                f16* xt = Xt + ((size_t)(nb * 1024) + mrow) * 32 + f;
                #pragma unroll
                for (int r = 0; r < 4; ++r) xt[r * 32] = co[r];
            } else {
                float* cp = Cpart + ((size_t)(blockIdx.z * NC + n)) * M + mrow;
                *(v4f*)cp = acc[i][j];
            }
        }
    }
}

// Combine split-K partials + recurrence epilogue (layer 1, fp16 state).
// Vectorized x4 (v4f partial reads, v4h state read/write). [R4 validated]
__global__ __launch_bounds__(256) void cheb_comb(
    const float* __restrict__ Cpart, const f16* __restrict__ Aprev,
    f16* __restrict__ C, int total, int nkc, float alpha, int useA)
{
    const int i4 = blockIdx.x * 256 + threadIdx.x;
    if (i4 * 4 >= total) return;
    const size_t b4 = (size_t)i4 * 4;
    float s[4] = {0.f, 0.f, 0.f, 0.f};
    for (int c = 0; c < nkc; ++c) {
        v4f p = *(const v4f*)(Cpart + (size_t)c * total + b4);
        #pragma unroll
        for (int r = 0; r < 4; ++r) s[r] += p[r];
    }
    v4h o;
    if (useA) {
        v4h a4 = *(const v4h*)(Aprev + b4);
        #pragma unroll
        for (int r = 0; r < 4; ++r) o[r] = (f16)(alpha * s[r] - (float)a4[r]);
    } else {
        #pragma unroll
        for (int r = 0; r < 4; ++r) o[r] = (f16)(alpha * s[r]);
    }
    *(v4h*)(C + b4) = o;
}

// ---------------------------------------------------------------------------
// Linear1 (25->32) + bias + relu + maxpool4 -> layer-2 slice0 (fp16) + Xt0.
// Each thread: 8 input m (16-B loads) -> 2 pooled outputs.
// ---------------------------------------------------------------------------
__global__ __launch_bounds__(256) void lin1_pool(
    const f16* __restrict__ S, const void* __restrict__ W1, const void* __restrict__ b1,
    const u32* __restrict__ meta, f16* __restrict__ O, f16* __restrict__ Xt0)
{
    const int flag = meta[0];
    const int g  = blockIdx.x * 64 + threadIdx.x;   // 0..511
    const int f  = blockIdx.y * 4 + threadIdx.y;    // 0..31
    const int n  = blockIdx.z;                      // 0..63
    float a[8];
    #pragma unroll
    for (int r = 0; r < 8; ++r) a[r] = 0.f;
    const size_t base = (size_t)n * 4096 + (size_t)g * 8;
    #pragma unroll
    for (int k = 0; k < 25; ++k) {
        v8h x8 = *(const v8h*)(S + (size_t)k * 262144 + base);
        float w = ldw(W1, k * 32 + f, flag);
        #pragma unroll
        for (int r = 0; r < 8; ++r) a[r] += (float)x8[r] * w;
    }
    const float b = ldw(b1, f, flag);
    float v0 = fmaxf(fmaxf(fmaxf(a[0], a[1]), fmaxf(a[2], a[3])) + b, 0.f);
    float v1 = fmaxf(fmaxf(fmaxf(a[4], a[5]), fmaxf(a[6], a[7])) + b, 0.f);
    const int m1 = g * 2;
    const size_t oi = ((size_t)n * 32 + f) * 1024 + m1;
    O[oi]     = (f16)v0;
    O[oi + 1] = (f16)v1;
    f16* xt = Xt0 + ((size_t)n * 1024 + m1) * 32 + f;
    xt[0]  = (f16)v0;
    xt[32] = (f16)v1;
}

// ---------------------------------------------------------------------------
// MFMA linear-2 accumulation over a group of slices (fp16 single).
// Xt ring has RS slots; slice k lives in slot k%RS (k0 is a multiple of RS).
// RS chosen at launch from ws_size (5 = R7-identical fallback).
// ---------------------------------------------------------------------------
__global__ __launch_bounds__(256) void lin2_mfma(
    const f16* __restrict__ XtBase, const f16* __restrict__ W2t16,
    float* __restrict__ acc, int k0, int cnt, int zi, int rs)
{
    const int tid  = threadIdx.x;
    const int wave = tid >> 6;
    const int lane = tid & 63;
    const int r16  = lane & 15;
    const int quad = lane >> 4;
    const int n  = blockIdx.y;
    const int u0 = blockIdx.x * 128 + wave * 32;

    v4f a[2][4];
    #pragma unroll
    for (int i = 0; i < 2; ++i)
        #pragma unroll
        for (int j = 0; j < 4; ++j) a[i][j] = (v4f){0.f, 0.f, 0.f, 0.f};

    for (int c = 0; c < cnt; ++c) {
        const f16* X = XtBase + (size_t)((k0 + c) % rs) * 2097152;
        v8h a0 = *(const v8h*)(X + ((size_t)n * 1024 + u0 + r16) * 32 + quad * 8);
        v8h a1 = *(const v8h*)(X + ((size_t)n * 1024 + u0 + 16 + r16) * 32 + quad * 8);
        const int kb = (k0 + c) * 32 + quad * 8;
        #pragma unroll
        for (int j = 0; j < 4; ++j) {
            v8h bh = *(const v8h*)(W2t16 + (size_t)(j * 16 + r16) * 800 + kb);
            a[0][j] = __builtin_amdgcn_mfma_f32_16x16x32_f16(a0, bh, a[0][j], 0, 0, 0);
            a[1][j] = __builtin_amdgcn_mfma_f32_16x16x32_f16(a1, bh, a[1][j], 0, 0, 0);
        }
    }

    #pragma unroll
    for (int i = 0; i < 2; ++i) {
        const int u = u0 + i * 16 + quad * 4;
        #pragma unroll
        for (int j = 0; j < 4; ++j) {
            const int fo = j * 16 + r16;
            float* p = acc + ((size_t)n * 1024 + u) * 64 + fo;
            if (zi) {
                #pragma unroll
                for (int r = 0; r < 4; ++r) p[r * 64] = a[i][j][r];
            } else {
                #pragma unroll
                for (int r = 0; r < 4; ++r) p[r * 64] += a[i][j][r];
            }
        }
    }
}

// Finish linear-2: bias + relu + maxpool4 -> hb16 bf16 hi/lo pair [n][16384]
__global__ __launch_bounds__(256) void lin2fin(
    const float* __restrict__ acc, const void* __restrict__ b2, const u32* __restrict__ meta,
    u16* __restrict__ hb16h, u16* __restrict__ hb16l)
{
    const int flag = meta[0];
    const int fo = threadIdx.x;
    const int m2 = blockIdx.x * 4 + threadIdx.y;
    const int n  = blockIdx.y;
    const size_t b = ((size_t)n * 1024 + (size_t)m2 * 4) * 64 + fo;
    float v = fmaxf(fmaxf(acc[b], acc[b + 64]), fmaxf(acc[b + 128], acc[b + 192]));
    v = fmaxf(v + ldw(b2, fo, flag), 0.f);
    const size_t oi = (size_t)n * 16384 + (size_t)m2 * 64 + fo;
    const u16 h = f2bf(v);
    hb16h[oi] = h;
    hb16l[oi] = f2bf(v - bf2f(h));
}

// ---------------------------------------------------------------------------
// FC1 via MFMA: (64 x 16384) @ (16384 x 512), split-K x128, no atomics.
// Grid (32 nt, 32 kg), 4 waves; wave kc = kg*4+wave (K-chunk 128).
// ---------------------------------------------------------------------------
__global__ __launch_bounds__(256) void fc1_mfma(
    const u16* __restrict__ hb16h, const u16* __restrict__ hb16l,
    const void* __restrict__ Wh, const u32* __restrict__ meta,
    float* __restrict__ part128)
{
    const int flag = meta[0];
    const int tid  = threadIdx.x;
    const int wave = tid >> 6;
    const int lane = tid & 63;
    const int r16  = lane & 15;
    const int quad = lane >> 4;
    const int nt = blockIdx.x;                 // 0..31 -> h-tile of 16
    const int kc = blockIdx.y * 4 + wave;      // 0..127 -> K-chunk of 128

    v4f acc[4];
    #pragma unroll
    for (int mt = 0; mt < 4; ++mt) acc[mt] = (v4f){0.f, 0.f, 0.f, 0.f};

    const int h0 = nt * 16 + r16;
    for (int ks = 0; ks < 4; ++ks) {
        const int kb = kc * 128 + ks * 32 + quad * 8;
        v8s bh, bl;
        #pragma unroll
        for (int j = 0; j < 8; ++j) {
            const float w = ldw(Wh, (size_t)(kb + j) * 512 + h0, flag);
            const u16 h = f2bf(w);
            bh[j] = (short)h;
            bl[j] = (short)f2bf(w - bf2f(h));
        }
        #pragma unroll
        for (int mt = 0; mt < 4; ++mt) {
            const size_t arow = (size_t)(mt * 16 + r16) * 16384 + kb;
            v8s ah = *(const v8s*)(hb16h + arow);
            v8s al = *(const v8s*)(hb16l + arow);
            acc[mt] = __builtin_amdgcn_mfma_f32_16x16x32_bf16(ah, bh, acc[mt], 0, 0, 0);
            acc[mt] = __builtin_amdgcn_mfma_f32_16x16x32_bf16(ah, bl, acc[mt], 0, 0, 0);
            acc[mt] = __builtin_amdgcn_mfma_f32_16x16x32_bf16(al, bh, acc[mt], 0, 0, 0);
        }
    }

    #pragma unroll
    for (int mt = 0; mt < 4; ++mt) {
        const int m = mt * 16 + quad * 4;
        float* p = part128 + (size_t)kc * 32768 + (size_t)m * 512 + h0;
        #pragma unroll
        for (int r = 0; r < 4; ++r) p[r * 512] = acc[mt][r];
    }
}

// Combine fc1 split-K partials: partC[idx] = sum_c part128[c][idx]
__global__ __launch_bounds__(256) void fc1comb(
    const float* __restrict__ part128, float* __restrict__ partC)
{
    const int idx = blockIdx.x * 256 + threadIdx.x;   // 0..32767
    float s = 0.f;
    #pragma unroll 8
    for (int c = 0; c < 128; ++c) s += part128[(size_t)c * 32768 + idx];
    partC[idx] = s;
}

// FC1 bias + relu fused with FC2
__global__ void fc2_k(
    const float* __restrict__ partC, const void* __restrict__ bh,
    const void* __restrict__ Wo, const void* __restrict__ bo,
    const u32* __restrict__ meta, void* __restrict__ out)
{
    const int flag = meta[0];
    const int n = blockIdx.x;
    const int lane = threadIdx.x;   // 64 = 1 wave
    float p[10];
    #pragma unroll
    for (int o = 0; o < 10; ++o) p[o] = 0.f;
    for (int j = lane; j < 512; j += 64) {
        const float r = fmaxf(partC[(size_t)n * 512 + j] + ldw(bh, j, flag), 0.f);
        #pragma unroll
        for (int o = 0; o < 10; ++o) p[o] += r * ldw(Wo, j * 10 + o, flag);
    }
    #pragma unroll
    for (int o = 0; o < 10; ++o) {
        for (int off = 32; off > 0; off >>= 1) p[o] += __shfl_down(p[o], off);
    }
    if (lane == 0) {
        #pragma unroll
        for (int o = 0; o < 10; ++o) {
            float v = p[o] + ldw(bo, o, flag);
            if (flag) ((u16*)out)[n * 10 + o] = f2bf(v);
            else      ((float*)out)[n * 10 + o] = v;
        }
    }
}

extern "C" void kernel_launch(void* const* d_in, const int* in_sizes, int n_in,
                              void* d_out, int out_size, void* d_ws, size_t ws_size,
                              hipStream_t stream)
{
    const void* x  = d_in[0];
    const void* L0 = d_in[1];
    const void* L1 = d_in[2];
    const void* W1 = d_in[3];
    const void* b1 = d_in[4];
    const void* W2 = d_in[5];
    const void* b2 = d_in[6];
    const void* Wh = d_in[7];
    const void* bh = d_in[8];
    const void* Wo = d_in[9];
    const void* bo = d_in[10];

    // ---- Xt ring size from ws_size (fallback RS=5 == R7 layout exactly) ----
    // base (non-Xt) usage = 82,940,160 B; each Xt slot = 4,194,304 B.
    const size_t XSLOT = 4194304;
    int RS = 5;
    if (ws_size >= (size_t)82940160 + 25 * XSLOT)      RS = 25;  // zero RMW
    else if (ws_size >= (size_t)82940160 + 10 * XSLOT) RS = 10;  // 2 RMW rounds

    // ---- workspace carve-up ----
    char* base = (char*)d_ws;
    size_t off = 0;
    u32* meta  = (u32*)(base + off);     off += 256;
    f16* L016  = (f16*)(base + off);     off += (size_t)16777216 * 2;
    f16* L116  = (f16*)(base + off);     off += (size_t)1048576 * 2;
    f16* A116  = (f16*)(base + off);     off += (size_t)25 * 262144 * 2;
    f16* A216  = (f16*)(base + off);     off += (size_t)3 * 2097152 * 2;
    f16* Xt16  = (f16*)(base + off);     off += (size_t)RS * 2097152 * 2;  // ring of RS
    float* ACC2 = (float*)(base + off);  off += (size_t)16777216;
    u16* hb16h = (u16*)(base + off);     off += (size_t)2097152;
    u16* hb16l = (u16*)(base + off);     off += (size_t)2097152;
    float* partC = (float*)(base + off); off += (size_t)131072 * 4;
    f16* W2t16 = (f16*)(base + off);     off += (size_t)102400;
    // Overlays on ACC2 (16.78 MB), used in disjoint phases:
    //   cpart  (8.39 MB) — layer-1 split-K partials, dead before lin2_mfma zi=1
    //   part128 (16.78 MB) — fc1 partials, ACC2 dead after lin2fin
    float* cpart   = ACC2;
    float* part128 = ACC2;

    // dtype detection + fp16 conversion + W2 transpose
    detect_k<<<1, 256, 0, stream>>>((const u32*)L0, meta);
    cvt_half<<<2048, 256, 0, stream>>>(L0, L016, meta, 16777216);
    cvt_half<<<256, 256, 0, stream>>>(L1, L116, meta, 1048576);
    cvt_half<<<64, 256, 0, stream>>>(x, A116, meta, 262144);   // slice 0
    w2t_k<<<200, 256, 0, stream>>>(W2, meta, W2t16);

    // ---- layer-1 Chebyshev recurrence: tiled split-K x8 + combine ----
    // [R3/R4/R7 validated optimum: 512 blocks = 2 blocks/CU, 8 waves/CU]
    for (int k = 1; k < 25; ++k) {
        cheb_tile<0><<<dim3(64, 1, 8), 256, 0, stream>>>(
            L016, A116 + (size_t)(k - 1) * 262144, (const f16*)0,
            (f16*)0, cpart, (f16*)0,
            4096, 4096, 64, 512, 0.f, 0);
        const f16* pA = (k >= 2) ? A116 + (size_t)(k - 2) * 262144 : A116;
        cheb_comb<<<256, 256, 0, stream>>>(
            cpart, pA, A116 + (size_t)k * 262144,
            262144, 8, (k == 1) ? 1.f : 2.f, (k >= 2) ? 1 : 0);
    }

    // linear1 + relu + pool4 -> layer-2 slice 0 (fp16) + transposed Xt slot 0
    lin1_pool<<<dim3(8, 8, 64), dim3(64, 4), 0, stream>>>(
        A116, W1, b1, meta, A216, Xt16);

    // ---- layer-2 recurrence (tiled, fused epilogue + Xt) + grouped MFMA lin2
    for (int k = 1; k < 25; ++k) {
        const f16* pB = A216 + (size_t)((k - 1) % 3) * 2097152;
        const f16* pA = A216 + (size_t)(((k >= 2) ? (k - 2) : 0) % 3) * 2097152;
        f16* pC = A216 + (size_t)(k % 3) * 2097152;
        cheb_tile<1><<<dim3(16, 32, 1), 256, 0, stream>>>(
            L116, pB, pA, pC, (float*)0, Xt16 + (size_t)(k % RS) * 2097152,
            1024, 1024, 2048, 1024, (k == 1) ? 1.f : 2.f, (k >= 2) ? 1 : 0);
        if ((k + 1) % RS == 0) {
            // slices k-RS+1..k occupy slots 0..RS-1 (k-RS+1 multiple of RS)
            const int k0g = k - RS + 1;
            lin2_mfma<<<dim3(8, 64), 256, 0, stream>>>(
                Xt16, W2t16, ACC2, k0g, RS, (k0g == 0) ? 1 : 0, RS);
        }
    }
    {   // tail group (25 % RS slices), if any
        const int rem = 25 % RS;
        if (rem) {
            const int k0g = 25 - rem;
            lin2_mfma<<<dim3(8, 64), 256, 0, stream>>>(
                Xt16, W2t16, ACC2, k0g, rem, (k0g == 0) ? 1 : 0, RS);
        }
    }

    // finish linear2: bias + relu + pool4 -> hb16 bf16 pair (ACC2 dead after)
    lin2fin<<<dim3(64, 64), dim3(64, 4), 0, stream>>>(ACC2, b2, meta, hb16h, hb16l);

    // FC head: MFMA fc1 (split-K x128, no atomics) + combine + fc2
    fc1_mfma<<<dim3(32, 32), 256, 0, stream>>>(hb16h, hb16l, Wh, meta, part128);
    fc1comb<<<128, 256, 0, stream>>>(part128, partC);
    fc2_k<<<64, 64, 0, stream>>>(partC, bh, Wo, bo, meta, d_out);
}

// Round 10
// 868.056 us; speedup vs baseline: 2.5503x; 1.0061x over previous
//
#include <hip/hip_runtime.h>

typedef unsigned short u16;
typedef unsigned int   u32;
typedef _Float16 f16;
typedef f16  v8h __attribute__((ext_vector_type(8)));
typedef f16  v4h __attribute__((ext_vector_type(4)));
typedef short v8s __attribute__((ext_vector_type(8)));
typedef float v4f __attribute__((ext_vector_type(4)));
typedef u16   v4u __attribute__((ext_vector_type(4)));

__device__ __forceinline__ float bf2f(u16 u) {
    union { float f; u32 i; } c; c.i = ((u32)u) << 16; return c.f;
}
__device__ __forceinline__ u16 f2bf(float f) {
    union { float f; u32 i; } c; c.f = f;
    u32 x = c.i;
    return (u16)((x + 0x7fffu + ((x >> 16) & 1u)) >> 16);
}
__device__ __forceinline__ float ldw(const void* p, long i, int flag) {
    return flag ? bf2f(((const u16*)p)[i]) : ((const float*)p)[i];
}

// ---------------------------------------------------------------------------
// dtype detector (round-3 validated: flag=0 on this harness -> fp32 inputs)
// ---------------------------------------------------------------------------
__global__ void detect_k(const u32* __restrict__ w, u32* __restrict__ meta) {
    __shared__ int cnt;
    if (threadIdx.x == 0) cnt = 0;
    __syncthreads();
    u32 v = w[(size_t)threadIdx.x * 4099];
    u32 f = (v >> 7) & 0xFFu;
    if (f >= 0x60u && f < 0x7Fu) atomicAdd(&cnt, 1);
    __syncthreads();
    if (threadIdx.x == 0) meta[0] = (cnt >= 192) ? 1u : 0u;
}

// Convert input (bf16 or fp32 per flag) -> fp16, 4 elems/thread.
__global__ void cvt_half(const void* __restrict__ in, f16* __restrict__ out,
                         const u32* __restrict__ meta, int n) {
    const int flag = meta[0];
    const int n4 = n >> 2;
    const int stride = gridDim.x * blockDim.x;
    for (int i = blockIdx.x * blockDim.x + threadIdx.x; i < n4; i += stride) {
        v4h o;
        if (flag) {
            v4u h = *(const v4u*)((const u16*)in + (size_t)i * 4);
            #pragma unroll
            for (int r = 0; r < 4; ++r) o[r] = (f16)bf2f(h[r]);
        } else {
            v4f v = *(const v4f*)((const float*)in + (size_t)i * 4);
            #pragma unroll
            for (int r = 0; r < 4; ++r) o[r] = (f16)v[r];
        }
        *(v4h*)(out + (size_t)i * 4) = o;
    }
}

// One-time W2 transpose: W2[f*25+kc][fo] -> W2t16[fo][kc*32+f] (fp16)
__global__ void w2t_k(const void* __restrict__ W2, const u32* __restrict__ meta,
                      f16* __restrict__ W2t16) {
    const int flag = meta[0];
    const int i = blockIdx.x * 256 + threadIdx.x;
    if (i >= 51200) return;
    const int k = i >> 6, fo = i & 63;
    const float w = ldw(W2, (size_t)k * 64 + fo, flag);
    const int f = k / 25, kc = k % 25;
    W2t16[(size_t)fo * 800 + kc * 32 + f] = (f16)w;
}

// ---------------------------------------------------------------------------
// Tiled Cheb GEMM (fp16 single-product): C = alpha*L@B - A
// Block: 64x64 tile, 256 thr = 4 waves (2x2), wave 32x32 via 2x2 MFMA
// 16x16x32 f16. Double-buffered LDS (36 KB; 2 blocks/CU), one barrier per
// K-stage, software pipeline depth 2 (P,Q register sets). [R7/R9 champion]
// FUSED=1: recurrence epilogue + Xt write (layer 2). FUSED=0: fp32 split-K
// partials (layer 1).
// ---------------------------------------------------------------------------
template<int FUSED>
__global__ __launch_bounds__(256) void cheb_tile(
    const f16* __restrict__ L, const f16* __restrict__ B, const f16* __restrict__ A,
    f16* __restrict__ C, float* __restrict__ Cpart, f16* __restrict__ Xt,
    int M, int V, int NC, int kc, float alpha, int useA)
{
    __shared__ f16 smem[2 * 2 * 64 * 72];        // dbuf x (A|B) x [64][72] = 36 KB
    const int tid  = threadIdx.x;
    const int wave = tid >> 6;
    const int lane = tid & 63;
    const int r16  = lane & 15;
    const int quad = lane >> 4;
    const int wm = wave & 1, wn = wave >> 1;

    const int m0 = blockIdx.x * 64;
    const int n0 = blockIdx.y * 64;
    const int k0 = blockIdx.z * kc;

    const int sr = lane >> 3;                    // 0..7
    const int sc = lane & 7;                     // 0..7
    const int rloc = wave * 16 + sr;             // row, j=0 (+8 rows for j=1)
    const int lw  = rloc * 72 + sc * 8;

    v4f acc[2][2];
    #pragma unroll
    for (int i = 0; i < 2; ++i)
        #pragma unroll
        for (int j = 0; j < 2; ++j) acc[i][j] = (v4f){0.f, 0.f, 0.f, 0.f};

    const int arow0 = (wm * 32 + r16) * 72;      // offsets within one 9216-elem buf
    const int arow1 = arow0 + 16 * 72;
    const int brow0 = 4608 + (wn * 32 + r16) * 72;
    const int brow1 = brow0 + 16 * 72;

    const int stages = kc >> 6;                  // 8 (layer 1) or 16 (layer 2); even
    const size_t j8  = (size_t)8 * V;
    const size_t gAr = (size_t)(m0 + rloc) * V + sc * 8;
    const size_t gBr = (size_t)(n0 + rloc) * V + sc * 8;

#define LOADG(KK, T0, T1, T2, T3) {                                   \
    const size_t gA = gAr + (size_t)(KK);                             \
    const size_t gB = gBr + (size_t)(KK);                             \
    T0 = *(const v8h*)(L + gA); T1 = *(const v8h*)(L + gA + j8);      \
    T2 = *(const v8h*)(B + gB); T3 = *(const v8h*)(B + gB + j8); }

#define WRITELDS(BUF, T0, T1, T2, T3) {                               \
    f16* sn = smem + (BUF) * 9216;                                    \
    *(v8h*)(sn +        lw)       = T0;                               \
    *(v8h*)(sn +        lw + 576) = T1;                               \
    *(v8h*)(sn + 4608 + lw)       = T2;                               \
    *(v8h*)(sn + 4608 + lw + 576) = T3; }

#define COMPUTE(BUF) {                                                \
    const f16* scur = smem + (BUF) * 9216;                            \
    _Pragma("unroll")                                                 \
    for (int s = 0; s < 2; ++s) {                                     \
        const int qo = (s * 4 + quad) * 8;                            \
        v8h a0 = *(const v8h*)(scur + arow0 + qo);                    \
        v8h a1 = *(const v8h*)(scur + arow1 + qo);                    \
        v8h b0 = *(const v8h*)(scur + brow0 + qo);                    \
        v8h b1 = *(const v8h*)(scur + brow1 + qo);                    \
        acc[0][0] = __builtin_amdgcn_mfma_f32_16x16x32_f16(a0, b0, acc[0][0], 0, 0, 0); \
        acc[0][1] = __builtin_amdgcn_mfma_f32_16x16x32_f16(a0, b1, acc[0][1], 0, 0, 0); \
        acc[1][0] = __builtin_amdgcn_mfma_f32_16x16x32_f16(a1, b0, acc[1][0], 0, 0, 0); \
        acc[1][1] = __builtin_amdgcn_mfma_f32_16x16x32_f16(a1, b1, acc[1][1], 0, 0, 0); } }

    // prologue: stage 0 -> LDS buf 0; prefetch stages 1 (P) and 2 (Q)
    {
        v8h t0, t1, t2, t3;
        LOADG(k0, t0, t1, t2, t3);
        WRITELDS(0, t0, t1, t2, t3);
    }
    v8h p0, p1, p2, p3, q0, q1, q2, q3;
    if (1 < stages) LOADG(k0 + 64,  p0, p1, p2, p3);
    if (2 < stages) LOADG(k0 + 128, q0, q1, q2, q3);
    __syncthreads();

    for (int st = 0; st < stages; st += 2) {
        // ---- stage st (even): compute buf 0 ----
        COMPUTE(0);
        if (st + 1 < stages) {
            WRITELDS(1, p0, p1, p2, p3);          // waits only P's loads
            if (st + 3 < stages) LOADG(k0 + (st + 3) * 64, p0, p1, p2, p3);
            __syncthreads();
            // ---- stage st+1 (odd): compute buf 1 ----
            COMPUTE(1);
            if (st + 2 < stages) {
                WRITELDS(0, q0, q1, q2, q3);
                if (st + 4 < stages) LOADG(k0 + (st + 4) * 64, q0, q1, q2, q3);
                __syncthreads();
            }
        }
    }

#undef LOADG
#undef WRITELDS
#undef COMPUTE

    #pragma unroll
    for (int j = 0; j < 2; ++j) {
        const int n = n0 + wn * 32 + j * 16 + r16;
        #pragma unroll
        for (int i = 0; i < 2; ++i) {
            const int mrow = m0 + wm * 32 + i * 16 + quad * 4;
            if (FUSED) {
                const size_t obase = (size_t)n * M + mrow;
                float vals[4];
                if (useA) {
                    v4h a4 = *(const v4h*)(A + obase);
                    #pragma unroll
                    for (int r = 0; r < 4; ++r)
                        vals[r] = alpha * acc[i][j][r] - (float)a4[r];
                } else {
                    #pragma unroll
                    for (int r = 0; r < 4; ++r) vals[r] = alpha * acc[i][j][r];
                }
                v4h co;
                #pragma unroll
                for (int r = 0; r < 4; ++r) co[r] = (f16)vals[r];
                *(v4h*)(C + obase) = co;
                // transposed copy for lin2 MFMA: Xt[(nb*1024 + u)*32 + f]
                const int nb = n >> 5, f = n & 31;
                f16* xt = Xt + ((size_t)(nb * 1024) + mrow) * 32 + f;
                #pragma unroll
                for (int r = 0; r < 4; ++r) xt[r * 32] = co[r];
            } else {
                float* cp = Cpart + ((size_t)(blockIdx.z * NC + n)) * M + mrow;
                *(v4f*)cp = acc[i][j];
            }
        }
    }
}

// Combine split-K partials + recurrence epilogue (layer 1, fp16 state).
// Vectorized x4 (v4f partial reads, v4h state read/write). [R4 validated]
__global__ __launch_bounds__(256) void cheb_comb(
    const float* __restrict__ Cpart, const f16* __restrict__ Aprev,
    f16* __restrict__ C, int total, int nkc, float alpha, int useA)
{
    const int i4 = blockIdx.x * 256 + threadIdx.x;
    if (i4 * 4 >= total) return;
    const size_t b4 = (size_t)i4 * 4;
    float s[4] = {0.f, 0.f, 0.f, 0.f};
    for (int c = 0; c < nkc; ++c) {
        v4f p = *(const v4f*)(Cpart + (size_t)c * total + b4);
        #pragma unroll
        for (int r = 0; r < 4; ++r) s[r] += p[r];
    }
    v4h o;
    if (useA) {
        v4h a4 = *(const v4h*)(Aprev + b4);
        #pragma unroll
        for (int r = 0; r < 4; ++r) o[r] = (f16)(alpha * s[r] - (float)a4[r]);
    } else {
        #pragma unroll
        for (int r = 0; r < 4; ++r) o[r] = (f16)(alpha * s[r]);
    }
    *(v4h*)(C + b4) = o;
}

// ---------------------------------------------------------------------------
// Linear1 (25->32) + bias + relu + maxpool4 -> layer-2 slice0 (fp16) + Xt0.
// Each thread: 8 input m (16-B loads) -> 2 pooled outputs.
// ---------------------------------------------------------------------------
__global__ __launch_bounds__(256) void lin1_pool(
    const f16* __restrict__ S, const void* __restrict__ W1, const void* __restrict__ b1,
    const u32* __restrict__ meta, f16* __restrict__ O, f16* __restrict__ Xt0)
{
    const int flag = meta[0];
    const int g  = blockIdx.x * 64 + threadIdx.x;   // 0..511
    const int f  = blockIdx.y * 4 + threadIdx.y;    // 0..31
    const int n  = blockIdx.z;                      // 0..63
    float a[8];
    #pragma unroll
    for (int r = 0; r < 8; ++r) a[r] = 0.f;
    const size_t base = (size_t)n * 4096 + (size_t)g * 8;
    #pragma unroll
    for (int k = 0; k < 25; ++k) {
        v8h x8 = *(const v8h*)(S + (size_t)k * 262144 + base);
        float w = ldw(W1, k * 32 + f, flag);
        #pragma unroll
        for (int r = 0; r < 8; ++r) a[r] += (float)x8[r] * w;
    }
    const float b = ldw(b1, f, flag);
    float v0 = fmaxf(fmaxf(fmaxf(a[0], a[1]), fmaxf(a[2], a[3])) + b, 0.f);
    float v1 = fmaxf(fmaxf(fmaxf(a[4], a[5]), fmaxf(a[6], a[7])) + b, 0.f);
    const int m1 = g * 2;
    const size_t oi = ((size_t)n * 32 + f) * 1024 + m1;
    O[oi]     = (f16)v0;
    O[oi + 1] = (f16)v1;
    f16* xt = Xt0 + ((size_t)n * 1024 + m1) * 32 + f;
    xt[0]  = (f16)v0;
    xt[32] = (f16)v1;
}

// ---------------------------------------------------------------------------
// FUSED linear-2 (RS=25 path): full 25-slice MFMA accumulation in registers,
// then pool4 + bias + relu + bf16 hi/lo write IN-EPILOGUE. ACC2 never
// materialized; replaces lin2_mfma+lin2fin pair. Fragment rows quad*4+r are
// 4 consecutive u = exactly one pool group (same arithmetic as lin2fin).
// ---------------------------------------------------------------------------
__global__ __launch_bounds__(256) void lin2_pool(
    const f16* __restrict__ XtBase, const f16* __restrict__ W2t16,
    const void* __restrict__ b2, const u32* __restrict__ meta,
    u16* __restrict__ hb16h, u16* __restrict__ hb16l)
{
    const int flag = meta[0];
    const int tid  = threadIdx.x;
    const int wave = tid >> 6;
    const int lane = tid & 63;
    const int r16  = lane & 15;
    const int quad = lane >> 4;
    const int n  = blockIdx.y;
    const int u0 = blockIdx.x * 128 + wave * 32;

    v4f a[2][4];
    #pragma unroll
    for (int i = 0; i < 2; ++i)
        #pragma unroll
        for (int j = 0; j < 4; ++j) a[i][j] = (v4f){0.f, 0.f, 0.f, 0.f};

    for (int c = 0; c < 25; ++c) {
        const f16* X = XtBase + (size_t)c * 2097152;
        v8h a0 = *(const v8h*)(X + ((size_t)n * 1024 + u0 + r16) * 32 + quad * 8);
        v8h a1 = *(const v8h*)(X + ((size_t)n * 1024 + u0 + 16 + r16) * 32 + quad * 8);
        const int kb = c * 32 + quad * 8;
        #pragma unroll
        for (int j = 0; j < 4; ++j) {
            v8h bh = *(const v8h*)(W2t16 + (size_t)(j * 16 + r16) * 800 + kb);
            a[0][j] = __builtin_amdgcn_mfma_f32_16x16x32_f16(a0, bh, a[0][j], 0, 0, 0);
            a[1][j] = __builtin_amdgcn_mfma_f32_16x16x32_f16(a1, bh, a[1][j], 0, 0, 0);
        }
    }

    #pragma unroll
    for (int i = 0; i < 2; ++i) {
        const int u  = u0 + i * 16 + quad * 4;    // 4-aligned -> one pool group
        const int m2 = u >> 2;
        #pragma unroll
        for (int j = 0; j < 4; ++j) {
            const int fo = j * 16 + r16;
            float v = fmaxf(fmaxf(a[i][j][0], a[i][j][1]),
                            fmaxf(a[i][j][2], a[i][j][3]));
            v = fmaxf(v + ldw(b2, fo, flag), 0.f);
            const size_t oi = (size_t)n * 16384 + (size_t)m2 * 64 + fo;
            const u16 h = f2bf(v);
            hb16h[oi] = h;
            hb16l[oi] = f2bf(v - bf2f(h));
        }
    }
}

// ---------------------------------------------------------------------------
// Fallback (RS<25): MFMA linear-2 accumulation over a group of slices into
// fp32 ACC (global RMW), ring slot k%RS. [validated rounds 1-9]
// ---------------------------------------------------------------------------
__global__ __launch_bounds__(256) void lin2_mfma(
    const f16* __restrict__ XtBase, const f16* __restrict__ W2t16,
    float* __restrict__ acc, int k0, int cnt, int zi, int rs)
{
    const int tid  = threadIdx.x;
    const int wave = tid >> 6;
    const int lane = tid & 63;
    const int r16  = lane & 15;
    const int quad = lane >> 4;
    const int n  = blockIdx.y;
    const int u0 = blockIdx.x * 128 + wave * 32;

    v4f a[2][4];
    #pragma unroll
    for (int i = 0; i < 2; ++i)
        #pragma unroll
        for (int j = 0; j < 4; ++j) a[i][j] = (v4f){0.f, 0.f, 0.f, 0.f};

    for (int c = 0; c < cnt; ++c) {
        const f16* X = XtBase + (size_t)((k0 + c) % rs) * 2097152;
        v8h a0 = *(const v8h*)(X + ((size_t)n * 1024 + u0 + r16) * 32 + quad * 8);
        v8h a1 = *(const v8h*)(X + ((size_t)n * 1024 + u0 + 16 + r16) * 32 + quad * 8);
        const int kb = (k0 + c) * 32 + quad * 8;
        #pragma unroll
        for (int j = 0; j < 4; ++j) {
            v8h bh = *(const v8h*)(W2t16 + (size_t)(j * 16 + r16) * 800 + kb);
            a[0][j] = __builtin_amdgcn_mfma_f32_16x16x32_f16(a0, bh, a[0][j], 0, 0, 0);
            a[1][j] = __builtin_amdgcn_mfma_f32_16x16x32_f16(a1, bh, a[1][j], 0, 0, 0);
        }
    }

    #pragma unroll
    for (int i = 0; i < 2; ++i) {
        const int u = u0 + i * 16 + quad * 4;
        #pragma unroll
        for (int j = 0; j < 4; ++j) {
            const int fo = j * 16 + r16;
            float* p = acc + ((size_t)n * 1024 + u) * 64 + fo;
            if (zi) {
                #pragma unroll
                for (int r = 0; r < 4; ++r) p[r * 64] = a[i][j][r];
            } else {
                #pragma unroll
                for (int r = 0; r < 4; ++r) p[r * 64] += a[i][j][r];
            }
        }
    }
}

// Finish linear-2 (RS<25 fallback): bias + relu + maxpool4 -> hb16 pair
__global__ __launch_bounds__(256) void lin2fin(
    const float* __restrict__ acc, const void* __restrict__ b2, const u32* __restrict__ meta,
    u16* __restrict__ hb16h, u16* __restrict__ hb16l)
{
    const int flag = meta[0];
    const int fo = threadIdx.x;
    const int m2 = blockIdx.x * 4 + threadIdx.y;
    const int n  = blockIdx.y;
    const size_t b = ((size_t)n * 1024 + (size_t)m2 * 4) * 64 + fo;
    float v = fmaxf(fmaxf(acc[b], acc[b + 64]), fmaxf(acc[b + 128], acc[b + 192]));
    v = fmaxf(v + ldw(b2, fo, flag), 0.f);
    const size_t oi = (size_t)n * 16384 + (size_t)m2 * 64 + fo;
    const u16 h = f2bf(v);
    hb16h[oi] = h;
    hb16l[oi] = f2bf(v - bf2f(h));
}

// ---------------------------------------------------------------------------
// FC1 via MFMA: (64 x 16384) @ (16384 x 512), split-K x128, no atomics.
// Grid (32 nt, 32 kg), 4 waves; wave kc = kg*4+wave (K-chunk 128).
// ---------------------------------------------------------------------------
__global__ __launch_bounds__(256) void fc1_mfma(
    const u16* __restrict__ hb16h, const u16* __restrict__ hb16l,
    const void* __restrict__ Wh, const u32* __restrict__ meta,
    float* __restrict__ part128)
{
    const int flag = meta[0];
    const int tid  = threadIdx.x;
    const int wave = tid >> 6;
    const int lane = tid & 63;
    const int r16  = lane & 15;
    const int quad = lane >> 4;
    const int nt = blockIdx.x;                 // 0..31 -> h-tile of 16
    const int kc = blockIdx.y * 4 + wave;      // 0..127 -> K-chunk of 128

    v4f acc[4];
    #pragma unroll
    for (int mt = 0; mt < 4; ++mt) acc[mt] = (v4f){0.f, 0.f, 0.f, 0.f};

    const int h0 = nt * 16 + r16;
    for (int ks = 0; ks < 4; ++ks) {
        const int kb = kc * 128 + ks * 32 + quad * 8;
        v8s bh, bl;
        #pragma unroll
        for (int j = 0; j < 8; ++j) {
            const float w = ldw(Wh, (size_t)(kb + j) * 512 + h0, flag);
            const u16 h = f2bf(w);
            bh[j] = (short)h;
            bl[j] = (short)f2bf(w - bf2f(h));
        }
        #pragma unroll
        for (int mt = 0; mt < 4; ++mt) {
            const size_t arow = (size_t)(mt * 16 + r16) * 16384 + kb;
            v8s ah = *(const v8s*)(hb16h + arow);
            v8s al = *(const v8s*)(hb16l + arow);
            acc[mt] = __builtin_amdgcn_mfma_f32_16x16x32_bf16(ah, bh, acc[mt], 0, 0, 0);
            acc[mt] = __builtin_amdgcn_mfma_f32_16x16x32_bf16(ah, bl, acc[mt], 0, 0, 0);
            acc[mt] = __builtin_amdgcn_mfma_f32_16x16x32_bf16(al, bh, acc[mt], 0, 0, 0);
        }
    }

    #pragma unroll
    for (int mt = 0; mt < 4; ++mt) {
        const int m = mt * 16 + quad * 4;
        float* p = part128 + (size_t)kc * 32768 + (size_t)m * 512 + h0;
        #pragma unroll
        for (int r = 0; r < 4; ++r) p[r * 512] = acc[mt][r];
    }
}

// Combine fc1 split-K partials: partC[idx] = sum_c part128[c][idx]
__global__ __launch_bounds__(256) void fc1comb(
    const float* __restrict__ part128, float* __restrict__ partC)
{
    const int idx = blockIdx.x * 256 + threadIdx.x;   // 0..32767
    float s = 0.f;
    #pragma unroll 8
    for (int c = 0; c < 128; ++c) s += part128[(size_t)c * 32768 + idx];
    partC[idx] = s;
}

// FC1 bias + relu fused with FC2
__global__ void fc2_k(
    const float* __restrict__ partC, const void* __restrict__ bh,
    const void* __restrict__ Wo, const void* __restrict__ bo,
    const u32* __restrict__ meta, void* __restrict__ out)
{
    const int flag = meta[0];
    const int n = blockIdx.x;
    const int lane = threadIdx.x;   // 64 = 1 wave
    float p[10];
    #pragma unroll
    for (int o = 0; o < 10; ++o) p[o] = 0.f;
    for (int j = lane; j < 512; j += 64) {
        const float r = fmaxf(partC[(size_t)n * 512 + j] + ldw(bh, j, flag), 0.f);
        #pragma unroll
        for (int o = 0; o < 10; ++o) p[o] += r * ldw(Wo, j * 10 + o, flag);
    }
    #pragma unroll
    for (int o = 0; o < 10; ++o) {
        for (int off = 32; off > 0; off >>= 1) p[o] += __shfl_down(p[o], off);
    }
    if (lane == 0) {
        #pragma unroll
        for (int o = 0; o < 10; ++o) {
            float v = p[o] + ldw(bo, o, flag);
            if (flag) ((u16*)out)[n * 10 + o] = f2bf(v);
            else      ((float*)out)[n * 10 + o] = v;
        }
    }
}

extern "C" void kernel_launch(void* const* d_in, const int* in_sizes, int n_in,
                              void* d_out, int out_size, void* d_ws, size_t ws_size,
                              hipStream_t stream)
{
    const void* x  = d_in[0];
    const void* L0 = d_in[1];
    const void* L1 = d_in[2];
    const void* W1 = d_in[3];
    const void* b1 = d_in[4];
    const void* W2 = d_in[5];
    const void* b2 = d_in[6];
    const void* Wh = d_in[7];
    const void* bh = d_in[8];
    const void* Wo = d_in[9];
    const void* bo = d_in[10];

    // ---- Xt ring size from ws_size (fallback RS=5 == R7 layout exactly) ----
    // base (non-Xt) usage = 82,940,160 B; each Xt slot = 4,194,304 B.
    const size_t XSLOT = 4194304;
    int RS = 5;
    if (ws_size >= (size_t)82940160 + 25 * XSLOT)      RS = 25;  // zero RMW, fused pool
    else if (ws_size >= (size_t)82940160 + 10 * XSLOT) RS = 10;  // 2 RMW rounds

    // ---- workspace carve-up ----
    char* base = (char*)d_ws;
    size_t off = 0;
    u32* meta  = (u32*)(base + off);     off += 256;
    f16* L016  = (f16*)(base + off);     off += (size_t)16777216 * 2;
    f16* L116  = (f16*)(base + off);     off += (size_t)1048576 * 2;
    f16* A116  = (f16*)(base + off);     off += (size_t)25 * 262144 * 2;
    f16* A216  = (f16*)(base + off);     off += (size_t)3 * 2097152 * 2;
    f16* Xt16  = (f16*)(base + off);     off += (size_t)RS * 2097152 * 2;  // ring of RS
    float* ACC2 = (float*)(base + off);  off += (size_t)16777216;
    u16* hb16h = (u16*)(base + off);     off += (size_t)2097152;
    u16* hb16l = (u16*)(base + off);     off += (size_t)2097152;
    float* partC = (float*)(base + off); off += (size_t)131072 * 4;
    f16* W2t16 = (f16*)(base + off);     off += (size_t)102400;
    // Overlays on ACC2 (16.78 MB), used in disjoint phases:
    //   cpart  (8.39 MB) — layer-1 split-K partials, dead before lin2 phase
    //   part128 (16.78 MB) — fc1 partials, ACC2 dead after lin2 phase
    float* cpart   = ACC2;
    float* part128 = ACC2;

    // dtype detection + fp16 conversion + W2 transpose
    detect_k<<<1, 256, 0, stream>>>((const u32*)L0, meta);
    cvt_half<<<2048, 256, 0, stream>>>(L0, L016, meta, 16777216);
    cvt_half<<<256, 256, 0, stream>>>(L1, L116, meta, 1048576);
    cvt_half<<<64, 256, 0, stream>>>(x, A116, meta, 262144);   // slice 0
    w2t_k<<<200, 256, 0, stream>>>(W2, meta, W2t16);

    // ---- layer-1 Chebyshev recurrence: tiled split-K x8 + combine ----
    // [R3/R4/R7 validated optimum: 512 blocks = 2 blocks/CU, 8 waves/CU]
    for (int k = 1; k < 25; ++k) {
        cheb_tile<0><<<dim3(64, 1, 8), 256, 0, stream>>>(
            L016, A116 + (size_t)(k - 1) * 262144, (const f16*)0,
            (f16*)0, cpart, (f16*)0,
            4096, 4096, 64, 512, 0.f, 0);
        const f16* pA = (k >= 2) ? A116 + (size_t)(k - 2) * 262144 : A116;
        cheb_comb<<<256, 256, 0, stream>>>(
            cpart, pA, A116 + (size_t)k * 262144,
            262144, 8, (k == 1) ? 1.f : 2.f, (k >= 2) ? 1 : 0);
    }

    // linear1 + relu + pool4 -> layer-2 slice 0 (fp16) + transposed Xt slot 0
    lin1_pool<<<dim3(8, 8, 64), dim3(64, 4), 0, stream>>>(
        A116, W1, b1, meta, A216, Xt16);

    // ---- layer-2 recurrence (tiled, fused epilogue + Xt) ----
    for (int k = 1; k < 25; ++k) {
        const f16* pB = A216 + (size_t)((k - 1) % 3) * 2097152;
        const f16* pA = A216 + (size_t)(((k >= 2) ? (k - 2) : 0) % 3) * 2097152;
        f16* pC = A216 + (size_t)(k % 3) * 2097152;
        cheb_tile<1><<<dim3(16, 32, 1), 256, 0, stream>>>(
            L116, pB, pA, pC, (float*)0, Xt16 + (size_t)(k % RS) * 2097152,
            1024, 1024, 2048, 1024, (k == 1) ? 1.f : 2.f, (k >= 2) ? 1 : 0);
        if (RS < 25 && (k + 1) % RS == 0) {
            const int k0g = k - RS + 1;
            lin2_mfma<<<dim3(8, 64), 256, 0, stream>>>(
                Xt16, W2t16, ACC2, k0g, RS, (k0g == 0) ? 1 : 0, RS);
        }
    }

    // ---- linear-2 finish ----
    if (RS == 25) {
        // single fused kernel: 25-slice MFMA + pool4 + bias + relu -> hb16
        lin2_pool<<<dim3(8, 64), 256, 0, stream>>>(
            Xt16, W2t16, b2, meta, hb16h, hb16l);
    } else {
        const int rem = 25 % RS;
        if (rem) {
            const int k0g = 25 - rem;
            lin2_mfma<<<dim3(8, 64), 256, 0, stream>>>(
                Xt16, W2t16, ACC2, k0g, rem, (k0g == 0) ? 1 : 0, RS);
        }
        lin2fin<<<dim3(64, 64), dim3(64, 4), 0, stream>>>(
            ACC2, b2, meta, hb16h, hb16l);
    }

    // FC head: MFMA fc1 (split-K x128, no atomics) + combine + fc2
    fc1_mfma<<<dim3(32, 32), 256, 0, stream>>>(hb16h, hb16l, Wh, meta, part128);
    fc1comb<<<128, 256, 0, stream>>>(part128, partC);
    fc2_k<<<64, 64, 0, stream>>>(partC, bh, Wo, bo, meta, d_out);
}